// Round 5
// baseline (695.672 us; speedup 1.0000x reference)
//
#include <hip/hip_runtime.h>
#include <hip/hip_bf16.h>

#define N_ENT  100000
#define N_REL2 1000
#define H      256
#define E_EDGES 320000
#define REL_ROWS_PAD 1024   // 1000 rel rows padded to 64-row multiple
#define DEG_BINS 64

typedef unsigned short u16;
typedef short bf16x8 __attribute__((ext_vector_type(8)));
typedef float floatx4 __attribute__((ext_vector_type(4)));

__device__ __forceinline__ u16 f2bf(float f) {
    unsigned x = __float_as_uint(f);
    unsigned r = (x + 0x7fffu + ((x >> 16) & 1u)) >> 16;  // RNE
    return (u16)r;
}

__device__ __forceinline__ ushort4 pack4(float4 v, float s) {
    return make_ushort4(f2bf(v.x * s), f2bf(v.y * s), f2bf(v.z * s), f2bf(v.w * s));
}

__device__ __forceinline__ float fast_tanh(float x) {
    float e = __expf(2.0f * x);
    return 1.0f - 2.0f * __builtin_amdgcn_rcpf(e + 1.0f);
}

__device__ __forceinline__ float dot4(float4 a, float4 b) {
    return (a.x * b.x + a.y * b.y) + (a.z * b.z + a.w * b.w);
}
__device__ __forceinline__ float dot4m(float4 a, float4 b, float4 h) {
    return ((a.x * b.x) * h.x + (a.y * b.y) * h.y) + ((a.z * b.z) * h.z + (a.w * b.w) * h.w);
}
// acc*sc + pr*v
__device__ __forceinline__ float4 sfme(float4 a, float sc, float pr, float4 v) {
    return make_float4(a.x * sc + pr * v.x, a.y * sc + pr * v.y,
                       a.z * sc + pr * v.z, a.w * sc + pr * v.w);
}
// acc*sc + pr*u*v
__device__ __forceinline__ float4 sfme2(float4 a, float sc, float pr, float4 u, float4 v) {
    return make_float4(a.x * sc + (pr * u.x) * v.x, a.y * sc + (pr * u.y) * v.y,
                       a.z * sc + (pr * u.z) * v.z, a.w * sc + (pr * u.w) * v.w);
}

// ---------------- CSR build ----------------

__global__ void hist_kernel(const int* __restrict__ dst, int* __restrict__ counts) {
    int i = blockIdx.x * blockDim.x + threadIdx.x;
    if (i < E_EDGES) atomicAdd(&counts[dst[i]], 1);
}

// scan over counts; also builds the degree histogram (two-level: LDS then global)
__global__ void scan1_kernel(const int* __restrict__ counts, int* __restrict__ offsets,
                             int* __restrict__ bsum, int* __restrict__ dbin) {
    __shared__ int buf[1024];
    __shared__ int lh[DEG_BINS];
    int t = threadIdx.x, i = blockIdx.x * 1024 + t;
    if (t < DEG_BINS) lh[t] = 0;
    int v = (i < N_ENT) ? counts[i] : 0;
    int acc = v;
    buf[t] = acc;
    __syncthreads();
    if (i < N_ENT) {
        int b = v > DEG_BINS - 1 ? DEG_BINS - 1 : v;
        atomicAdd(&lh[b], 1);   // LDS atomic
    }
    for (int off = 1; off < 1024; off <<= 1) {
        int u = (t >= off) ? buf[t - off] : 0;
        __syncthreads();
        acc += u;
        buf[t] = acc;
        __syncthreads();
    }
    if (i < N_ENT) offsets[i] = acc - v;  // exclusive within block
    if (t == 1023) bsum[blockIdx.x] = acc;
    if (t < DEG_BINS && lh[t]) atomicAdd(&dbin[t], lh[t]);  // 64 global atomics/block
}

__global__ void scan2_kernel(int* __restrict__ bsum, int* __restrict__ offsets,
                             const int* __restrict__ dbin, int* __restrict__ doff) {
    __shared__ int s[128];
    int t = threadIdx.x;
    s[t] = (t < 98) ? bsum[t] : 0;
    __syncthreads();
    if (t == 0) {
        int run = 0;
        for (int b = 0; b < 98; ++b) { int x = s[b]; s[b] = run; run += x; }
        offsets[N_ENT] = run;
        int r2 = 0;
        for (int b = 0; b < DEG_BINS; ++b) { int x = dbin[b]; doff[b] = r2; r2 += x; }
    }
    __syncthreads();
    if (t < 98) bsum[t] = s[t];
}

__global__ void scan3_kernel(int* __restrict__ offsets, const int* __restrict__ bsum) {
    int i = blockIdx.x * 1024 + threadIdx.x;
    if (i < N_ENT && blockIdx.x > 0) offsets[i] += bsum[blockIdx.x];
}

// degree-sort placement: LDS rank + one global range-reserve atomic per (block,bin)
__global__ void degplace_kernel(const int* __restrict__ counts, int* __restrict__ doff,
                                int* __restrict__ dorder) {
    __shared__ int lh[DEG_BINS];
    __shared__ int lbase[DEG_BINS];
    int t = threadIdx.x;
    if (t < DEG_BINS) lh[t] = 0;
    __syncthreads();
    int i = blockIdx.x * blockDim.x + t;
    int b = 0, myidx = 0;
    if (i < N_ENT) {
        b = counts[i]; if (b > DEG_BINS - 1) b = DEG_BINS - 1;
        myidx = atomicAdd(&lh[b], 1);  // LDS atomic: intra-block rank
    }
    __syncthreads();
    if (t < DEG_BINS) lbase[t] = lh[t] ? atomicAdd(&doff[t], lh[t]) : 0;  // range reserve
    __syncthreads();
    if (i < N_ENT) dorder[lbase[b] + myidx] = i;
}

// place: resolve the whole per-edge metadata chain HERE (edge-parallel, coalesced
// reads) so scatter's per-edge chain is ONE 8B load: meta[pos] = {node_id[src], rel_id}
__global__ void place_kernel(const int* __restrict__ dst, const int* __restrict__ src,
                             const int* __restrict__ rel_id, const int* __restrict__ node_id,
                             const int* __restrict__ offsets,
                             int* __restrict__ counts, int2* __restrict__ meta) {
    int i = blockIdx.x * blockDim.x + threadIdx.x;
    if (i < E_EDGES) {
        int d = dst[i];
        int old = atomicSub(&counts[d], 1);
        meta[offsets[d] + old - 1] = make_int2(node_id[src[i]], rel_id[i]);
    }
}

// ---------------- weight prep ----------------
// B-fragment order for mfma_f32_16x16x32_bf16 (verified R1 of prior session):
// dst[((ntile*8+kstep)*64+lane)*8+j] = bf16(W[kstep*32+(lane>>4)*8+j][ntile*16+(lane&15)])
__global__ void swz_kernel(const float* __restrict__ w0, const float* __restrict__ w1,
                           const float* __restrict__ w2, const float* __restrict__ w3,
                           u16* __restrict__ dstp) {
    int t = blockIdx.x * blockDim.x + threadIdx.x;
    if (t >= 4 * H * H) return;
    int mat = t >> 16;
    int r = t & 65535;
    int j = r & 7, lane = (r >> 3) & 63, kstep = (r >> 9) & 7, ntile = r >> 12;
    int k = kstep * 32 + (lane >> 4) * 8 + j;
    int n = ntile * 16 + (lane & 15);
    const float* W = (mat == 0) ? w0 : (mat == 1) ? w1 : (mat == 2) ? w2 : w3;
    dstp[t] = f2bf(W[k * H + n]);
}

// rel_emb -> bf16, plain row-major (A rows read directly by the GEMM from global)
__global__ void relbf_kernel(const float* __restrict__ rel, u16* __restrict__ out) {
    int t = blockIdx.x * blockDim.x + threadIdx.x;
    if (t >= REL_ROWS_PAD * H) return;
    int row = t >> 8, k = t & 255;
    float v = (row < N_REL2) ? rel[row * H + k] : 0.f;
    out[t] = f2bf(v);
}

// ---------------- fused per-dst scores + softmax + segment-sum ----------------
// 16-lane-group version: each group of 16 lanes owns ONE destination (16 floats/lane
// = full H row per group); a wave processes 4 dsts concurrently. Degree sort makes
// the 4 groups' trip counts (near-)equal -> negligible intra-wave divergence.
__global__ __launch_bounds__(256) void scatter_kernel(
    const float* __restrict__ ent, const float* __restrict__ rel,
    const int2* __restrict__ meta, const int* __restrict__ node_id,
    const int* __restrict__ offsets, const int* __restrict__ dorder,
    u16* __restrict__ agg_e, u16* __restrict__ agg_n, u16* __restrict__ agg_c) {
    int lane = threadIdx.x & 63;
    int wv = threadIdx.x >> 6;
    int grp = lane >> 4, sl = lane & 15;
    int w = blockIdx.x * 16 + wv * 4 + grp;   // 6250*16 == 100000 exactly, no guard
    int d = dorder[w];
    int nid = node_id[d];
    int p0 = offsets[d], p1 = offsets[d + 1];
    // interleaved chunk assignment: lane sl holds float4 chunks {sl, 16+sl, 32+sl, 48+sl}
    // -> each load instruction reads 256B contiguous per group (perfect coalescing).
    const float4* hrow = (const float4*)(ent + (size_t)nid * H);
    float4 h0 = hrow[sl], h1 = hrow[16 + sl], h2 = hrow[32 + sl], h3 = hrow[48 + sl];
    float me = -INFINITY, mn = -INFINITY, mc = -INFINITY;
    float le = 0.f, ln = 0.f, lc = 0.f;
    float4 z = make_float4(0.f, 0.f, 0.f, 0.f);
    float4 ae0 = z, ae1 = z, ae2 = z, ae3 = z;
    float4 an0 = z, an1 = z, an2 = z, an3 = z;
    float4 ac0 = z, ac1 = z, ac2 = z, ac3 = z;

    for (int pc = p0; pc < p1; ++pc) {
        int2 md = meta[pc];   // 8B, uniform within group
        const float4* er = (const float4*)(rel + (size_t)md.y * H);
        const float4* sr = (const float4*)(ent + (size_t)md.x * H);
        float4 e0 = er[sl], e1 = er[16 + sl], e2 = er[32 + sl], e3 = er[48 + sl];
        float4 s0 = sr[sl], s1 = sr[16 + sl], s2 = sr[32 + sl], s3 = sr[48 + sl];
        float de = dot4(e0, h0) + dot4(e1, h1) + dot4(e2, h2) + dot4(e3, h3);
        float dn = dot4(s0, h0) + dot4(s1, h1) + dot4(s2, h2) + dot4(s3, h3);
        float dc = dot4m(e0, s0, h0) + dot4m(e1, s1, h1) + dot4m(e2, s2, h2) + dot4m(e3, s3, h3);
#pragma unroll
        for (int o = 8; o; o >>= 1) {   // in-group butterfly (xor<16 stays in group)
            de += __shfl_xor(de, o);
            dn += __shfl_xor(dn, o);
            dc += __shfl_xor(dc, o);
        }
        { float nm = fmaxf(me, de); float sc = __expf(me - nm); float pr = __expf(de - nm);
          le = le * sc + pr;
          ae0 = sfme(ae0, sc, pr, e0); ae1 = sfme(ae1, sc, pr, e1);
          ae2 = sfme(ae2, sc, pr, e2); ae3 = sfme(ae3, sc, pr, e3); me = nm; }
        { float nm = fmaxf(mn, dn); float sc = __expf(mn - nm); float pr = __expf(dn - nm);
          ln = ln * sc + pr;
          an0 = sfme(an0, sc, pr, s0); an1 = sfme(an1, sc, pr, s1);
          an2 = sfme(an2, sc, pr, s2); an3 = sfme(an3, sc, pr, s3); mn = nm; }
        { float nm = fmaxf(mc, dc); float sc = __expf(mc - nm); float pr = __expf(dc - nm);
          lc = lc * sc + pr;
          ac0 = sfme2(ac0, sc, pr, e0, s0); ac1 = sfme2(ac1, sc, pr, e1, s1);
          ac2 = sfme2(ac2, sc, pr, e2, s2); ac3 = sfme2(ac3, sc, pr, e3, s3); mc = nm; }
    }
    float ie  = (le > 0.f) ? 1.0f / le : 0.f;
    float in_ = (ln > 0.f) ? 1.0f / ln : 0.f;
    float ic  = (lc > 0.f) ? 1.0f / lc : 0.f;
    // plain row-major store: feature f of row d at byte 2f (no swizzle — the GEMM
    // reads A fragments directly from global now, no LDS in the consumer).
    size_t rowb = (size_t)d * 512;
    int b0 = sl * 8;
    *(ushort4*)((char*)agg_e + rowb + b0      ) = pack4(ae0, ie);
    *(ushort4*)((char*)agg_e + rowb + b0 + 128) = pack4(ae1, ie);
    *(ushort4*)((char*)agg_e + rowb + b0 + 256) = pack4(ae2, ie);
    *(ushort4*)((char*)agg_e + rowb + b0 + 384) = pack4(ae3, ie);
    *(ushort4*)((char*)agg_n + rowb + b0      ) = pack4(an0, in_);
    *(ushort4*)((char*)agg_n + rowb + b0 + 128) = pack4(an1, in_);
    *(ushort4*)((char*)agg_n + rowb + b0 + 256) = pack4(an2, in_);
    *(ushort4*)((char*)agg_n + rowb + b0 + 384) = pack4(an3, in_);
    *(ushort4*)((char*)agg_c + rowb + b0      ) = pack4(ac0, ic);
    *(ushort4*)((char*)agg_c + rowb + b0 + 128) = pack4(ac1, ic);
    *(ushort4*)((char*)agg_c + rowb + b0 + 256) = pack4(ac2, ic);
    *(ushort4*)((char*)agg_c + rowb + b0 + 384) = pack4(ac3, ic);
}

// ---------------- fused multi-layer GEMM epilogue ----------------
// out[r,:] = base[r,:] + sum_l tanh(A_l[r,:] @ W_l)   (raw if !do_tanh)
// 64 rows x 256 cols per block, 4 waves. NO LDS: each wave loads its A fragments
// directly from global (4x A re-read, absorbed by L1/L2/L3 — A is scatter-hot);
// zero barriers, zero bank conflicts, 4 waves/SIMD occupancy.
// A fragment for lane (m,quad): row rt*16+m, bytes ks*64+quad*16 — a b128 load.
__global__ __launch_bounds__(256, 4) void gemm_kernel(
    const u16* __restrict__ A0, const u16* __restrict__ A1, const u16* __restrict__ A2,
    const u16* __restrict__ W0, const u16* __restrict__ W1, const u16* __restrict__ W2,
    const float* __restrict__ base, float* __restrict__ out,
    int n_real, int n_layers, int do_tanh) {
    int tid = threadIdx.x;
    int lane = tid & 63;
    int wv = tid >> 6;
    int m = lane & 15;
    int quad = lane >> 4;
    int r0 = blockIdx.x * 64;
    const u16* As[3] = { A0, A1, A2 };
    const u16* Ws[3] = { W0, W1, W2 };

    float outacc[4][4][4];
#pragma unroll
    for (int rt = 0; rt < 4; ++rt)
#pragma unroll
        for (int ct = 0; ct < 4; ++ct) {
            int grow = r0 + rt * 16 + quad * 4;
            int gcol = wv * 64 + ct * 16 + m;
#pragma unroll
            for (int r = 0; r < 4; ++r) {
                float v = 0.f;
                if (base != nullptr && (grow + r) < n_real) v = base[(size_t)(grow + r) * H + gcol];
                outacc[rt][ct][r] = v;
            }
        }

    for (int l = 0; l < n_layers; ++l) {
        const char* Al = (const char*)(As[l]) + (size_t)r0 * 512;  // 512B per row
        const u16* Wl = Ws[l];

        floatx4 lacc[4][4];
#pragma unroll
        for (int rt = 0; rt < 4; ++rt)
#pragma unroll
            for (int ct = 0; ct < 4; ++ct)
#pragma unroll
                for (int r = 0; r < 4; ++r) lacc[rt][ct][r] = 0.f;

#pragma unroll
        for (int ks = 0; ks < 8; ++ks) {
            bf16x8 af[4], bfr[4];
#pragma unroll
            for (int rt = 0; rt < 4; ++rt)
                af[rt] = *(const bf16x8*)(Al + (size_t)(rt * 16 + m) * 512 + ks * 64 + quad * 16);
#pragma unroll
            for (int ct = 0; ct < 4; ++ct)
                bfr[ct] = *(const bf16x8*)(Wl + (((size_t)(wv * 4 + ct) * 8 + ks) * 64 + lane) * 8);
#pragma unroll
            for (int rt = 0; rt < 4; ++rt)
#pragma unroll
                for (int ct = 0; ct < 4; ++ct)
                    lacc[rt][ct] = __builtin_amdgcn_mfma_f32_16x16x32_bf16(
                        af[rt], bfr[ct], lacc[rt][ct], 0, 0, 0);
        }

#pragma unroll
        for (int rt = 0; rt < 4; ++rt)
#pragma unroll
            for (int ct = 0; ct < 4; ++ct)
#pragma unroll
                for (int r = 0; r < 4; ++r) {
                    float v = lacc[rt][ct][r];
                    outacc[rt][ct][r] += do_tanh ? fast_tanh(v) : v;
                }
    }

#pragma unroll
    for (int rt = 0; rt < 4; ++rt)
#pragma unroll
        for (int ct = 0; ct < 4; ++ct) {
            int grow = r0 + rt * 16 + quad * 4;
            int gcol = wv * 64 + ct * 16 + m;
#pragma unroll
            for (int r = 0; r < 4; ++r)
                if ((grow + r) < n_real) out[(size_t)(grow + r) * H + gcol] = outacc[rt][ct][r];
        }
}

// ---------------- launch ----------------

extern "C" void kernel_launch(void* const* d_in, const int* in_sizes, int n_in,
                              void* d_out, int out_size, void* d_ws, size_t ws_size,
                              hipStream_t stream) {
    (void)in_sizes; (void)n_in; (void)out_size; (void)ws_size;
    const float* ent    = (const float*)d_in[0];
    const float* rel    = (const float*)d_in[1];
    const float* w_edge = (const float*)d_in[2];
    const float* w_node = (const float*)d_in[3];
    const float* w_comp = (const float*)d_in[4];
    const float* rel_w  = (const float*)d_in[5];
    const int* src      = (const int*)d_in[6];
    const int* dst      = (const int*)d_in[7];
    const int* rel_id   = (const int*)d_in[8];
    const int* node_id  = (const int*)d_in[9];

    char* wsb = (char*)d_ws;
    size_t o = 0;
    auto alloc = [&](size_t bytes) -> char* {
        char* p = wsb + o;
        o = (o + bytes + 255) & ~(size_t)255;
        return p;
    };
    int* counts  = (int*)alloc((size_t)N_ENT * 4);
    int* offsets = (int*)alloc((size_t)(N_ENT + 1) * 4);
    int* bsum    = (int*)alloc(128 * 4);
    int2* meta   = (int2*)alloc((size_t)E_EDGES * 8);
    int* dbin    = (int*)alloc(DEG_BINS * 4);
    int* doff    = (int*)alloc(DEG_BINS * 4);
    int* dorder  = (int*)alloc((size_t)N_ENT * 4);
    u16* agg_e   = (u16*)alloc((size_t)N_ENT * H * 2);
    u16* agg_n   = (u16*)alloc((size_t)N_ENT * H * 2);
    u16* agg_c   = (u16*)alloc((size_t)N_ENT * H * 2);
    u16* wswz    = (u16*)alloc((size_t)4 * H * H * 2);
    u16* relbf   = (u16*)alloc((size_t)REL_ROWS_PAD * H * 2);
    (void)alloc(65536);  // overrun pad for tail-block A reads

    float* out_ent = (float*)d_out;
    float* out_rel = out_ent + (size_t)N_ENT * H;

    hipMemsetAsync(counts, 0, (size_t)N_ENT * 4, stream);
    hipMemsetAsync(dbin, 0, DEG_BINS * 4, stream);
    hist_kernel<<<(E_EDGES + 255) / 256, 256, 0, stream>>>(dst, counts);
    scan1_kernel<<<98, 1024, 0, stream>>>(counts, offsets, bsum, dbin);
    scan2_kernel<<<1, 128, 0, stream>>>(bsum, offsets, dbin, doff);
    scan3_kernel<<<98, 1024, 0, stream>>>(offsets, bsum);
    degplace_kernel<<<98, 1024, 0, stream>>>(counts, doff, dorder);
    place_kernel<<<(E_EDGES + 255) / 256, 256, 0, stream>>>(dst, src, rel_id, node_id,
                                                            offsets, counts, meta);
    swz_kernel<<<(4 * H * H + 255) / 256, 256, 0, stream>>>(w_edge, w_node, w_comp, rel_w, wswz);
    relbf_kernel<<<(REL_ROWS_PAD * H + 255) / 256, 256, 0, stream>>>(rel, relbf);
    scatter_kernel<<<N_ENT / 16, 256, 0, stream>>>(ent, rel, meta, node_id, offsets, dorder,
                                                   agg_e, agg_n, agg_c);
    gemm_kernel<<<(N_ENT + 63) / 64, 256, 0, stream>>>(agg_e, agg_n, agg_c,
                                                       wswz, wswz + H * H, wswz + 2 * H * H,
                                                       ent, out_ent, N_ENT, 3, 1);
    gemm_kernel<<<(N_REL2 + 63) / 64, 256, 0, stream>>>(relbf, relbf, relbf,
                                                        wswz + 3 * H * H, wswz + 3 * H * H, wswz + 3 * H * H,
                                                        nullptr, out_rel, N_REL2, 1, 0);
}